// Round 18
// baseline (212.517 us; speedup 1.0000x reference)
//
#include <hip/hip_runtime.h>
#include <math.h>

#define NN 4096
#define DD 512
#define NC 10
#define NG 2

#define BM 128
#define BN 128
#define BK 32
#define NT (DD / BK)     // 16 K-steps
#define NTILES 2080      // 528 TT + 528 SS + 1024 TS (= 8 * 260)

typedef __bf16 bf16x8 __attribute__((ext_vector_type(8)));
typedef __bf16 bf16x4 __attribute__((ext_vector_type(4)));
typedef float f32x4 __attribute__((ext_vector_type(4)));

__device__ __forceinline__ float agent_ld(const float* p) {
    return __hip_atomic_load(p, __ATOMIC_RELAXED, __HIP_MEMORY_SCOPE_AGENT);
}

// ---------------------------------------------------------------------------
// Kernel 1 (fused): fp32->bf16 convert + per-row norms (all 1024 blocks)
// + column sums / sumsq partials (blocks 0..63) + last-heavy-block invscale.
// (unchanged from round 16)
// ---------------------------------------------------------------------------
__global__ void k_prep(const float* __restrict__ ft, const float* __restrict__ fs,
                       __bf16* __restrict__ at, __bf16* __restrict__ as_,
                       float* __restrict__ nt, float* __restrict__ ns,
                       float* __restrict__ psum, float* __restrict__ ssq,
                       float* __restrict__ gbkt, float* __restrict__ invscale,
                       unsigned int* __restrict__ cnt) {
    int tid = threadIdx.x;
    if (blockIdx.x == 0 && tid < 64) gbkt[tid] = 0.0f;

    int wid  = tid >> 6;
    int lane = tid & 63;
    int r = blockIdx.x * 4 + wid;             // 0..4095
    const float4* pt = (const float4*)(ft + (size_t)r * DD);
    const float4* ps = (const float4*)(fs + (size_t)r * DD);
    float st = 0.0f, ss = 0.0f;
#pragma unroll
    for (int c = 0; c < 2; ++c) {
        float4 vt = pt[lane + 64 * c];
        float4 vs = ps[lane + 64 * c];
        st += vt.x * vt.x + vt.y * vt.y + vt.z * vt.z + vt.w * vt.w;
        ss += vs.x * vs.x + vs.y * vs.y + vs.z * vs.z + vs.w * vs.w;
        bf16x4 bt, bs;
        bt[0] = (__bf16)vt.x; bt[1] = (__bf16)vt.y; bt[2] = (__bf16)vt.z; bt[3] = (__bf16)vt.w;
        bs[0] = (__bf16)vs.x; bs[1] = (__bf16)vs.y; bs[2] = (__bf16)vs.z; bs[3] = (__bf16)vs.w;
        *(bf16x4*)(at  + (size_t)r * DD + (lane + 64 * c) * 4) = bt;
        *(bf16x4*)(as_ + (size_t)r * DD + (lane + 64 * c) * 4) = bs;
    }
#pragma unroll
    for (int o = 32; o; o >>= 1) { st += __shfl_xor(st, o); ss += __shfl_xor(ss, o); }
    if (lane == 0) { nt[r] = st; ns[r] = ss; }

    if (blockIdx.x >= 64) return;
    int b = blockIdx.x;
    const float* src = (b < 32) ? ft : fs;
    int r0 = (b & 31) * 128;
    int c0 = tid, c1 = tid + 256;
    float a0 = 0.0f, a1 = 0.0f, sq = 0.0f;
    for (int rr = r0; rr < r0 + 128; ++rr) {
        float v0 = src[(size_t)rr * DD + c0];
        float v1 = src[(size_t)rr * DD + c1];
        a0 += v0; a1 += v1;
        sq += v0 * v0 + v1 * v1;
    }
    psum[(size_t)b * 512 + c0] = a0;
    psum[(size_t)b * 512 + c1] = a1;
#pragma unroll
    for (int o = 32; o; o >>= 1) sq += __shfl_xor(sq, o);
    __shared__ float redsq[4];
    if (lane == 0) redsq[wid] = sq;
    __syncthreads();
    if (tid == 0) ssq[b] = redsq[0] + redsq[1] + redsq[2] + redsq[3];

    __shared__ int amLast;
    __threadfence();
    __syncthreads();
    if (tid == 0) amLast = (atomicAdd(cnt, 1u) == 63u) ? 1 : 0;
    __syncthreads();
    if (!amLast) return;
    __threadfence();

    __shared__ float red[8];
    float s = (tid < 64) ? agent_ld(&ssq[tid]) : 0.0f;
    float d = 0.0f;
    for (int col = tid; col < DD; col += 256) {
        float su = 0.0f, sv = 0.0f;
#pragma unroll
        for (int p = 0; p < 32; ++p) {
            su += agent_ld(&psum[(size_t)p * 512 + col]);
            sv += agent_ld(&psum[(size_t)(p + 32) * 512 + col]);
        }
        d += su * sv;
    }
#pragma unroll
    for (int o = 32; o; o >>= 1) { s += __shfl_xor(s, o); d += __shfl_xor(d, o); }
    if (lane == 0) { red[wid] = s; red[wid + 4] = d; }
    __syncthreads();
    if (tid == 0) {
        float S  = red[0] + red[1] + red[2] + red[3];
        float Dt = red[4] + red[5] + red[6] + red[7];
        float sigma = S / (float)NN - 2.0f * Dt / ((float)NN * (float)NN);
        invscale[0] = 1.0f / (2.0f * sigma);
    }
}

// ---------------------------------------------------------------------------
// Kernel 2: all three Grams, BARRIER-FREE direct-global (L2-resident data):
// no LDS staging at all — each lane loads its MFMA fragments straight from
// global into registers (16B aligned bf16x8; same lane<->element mapping the
// LDS path delivered, so accumulation order is bit-identical). Register
// double-buffer one K-step ahead; full unroll -> static ping-pong regs and
// compile-time offset immediates (<=960B). Zero barriers / zero LDS traffic
// in the K-loop; waves free-run and the CU co-schedules MFMA + VMEM pipes.
// Geometry: r16's best — 128x128 tile, 4 waves (2x2), wave tile 64x64,
// acc[4][4]; 2080-tile triangle space, swz=(bid&7)*260+bid>>3.
// Epilogue: LDS bucket reduce -> <=20 atomics into gbkt[50]. (r16 proven)
// ---------------------------------------------------------------------------
__global__ __launch_bounds__(256, 3) void k_gram_all(
    const __bf16* __restrict__ T, const __bf16* __restrict__ S,
    const float* __restrict__ nt, const float* __restrict__ ns,
    const int* __restrict__ labels, const int* __restrict__ groups,
    const float* __restrict__ invscale_p, float* __restrict__ gbkt) {

    __shared__ float lbkt[20];

    int swz = ((int)blockIdx.x & 7) * 260 + ((int)blockIdx.x >> 3);
    int mode, bi, bj;
    if (swz < 1056) {
        mode = (swz < 528) ? 0 : 1;
        int k = (swz < 528) ? swz : swz - 528;
        int t = 0;
        while (k >= 32 - t) { k -= 32 - t; ++t; }   // uniform, <=32 iters
        bi = t; bj = t + k;
    } else {
        mode = 2;
        int k = swz - 1056;
        bi = k >> 5; bj = k & 31;
    }

    const __bf16* A = (mode == 1) ? S : T;
    const __bf16* B = (mode == 0) ? T : S;
    const float* nA = (mode == 1) ? ns : nt;
    const float* nB = (mode == 0) ? nt : ns;

    int tid = threadIdx.x;
    if (tid < 20) lbkt[tid] = 0.0f;
    __syncthreads();                         // lbkt visible to all waves

    int i0 = bi * BM;
    int j0 = bj * BN;

    int lane = tid & 63, wid = tid >> 6;
    int wr = wid >> 1, wc = wid & 1;          // 2 x 2 wave grid
    int l15 = lane & 15, l4 = lane >> 4;

    // fixed per-lane fragment base pointers; K advances via imm offsets
    const __bf16* pA[4];
    const __bf16* pB[4];
#pragma unroll
    for (int im = 0; im < 4; ++im)
        pA[im] = A + (size_t)(i0 + wr * 64 + im * 16 + l15) * DD + l4 * 8;
#pragma unroll
    for (int in = 0; in < 4; ++in)
        pB[in] = B + (size_t)(j0 + wc * 64 + in * 16 + l15) * DD + l4 * 8;

    f32x4 acc[4][4] = {};
    bf16x8 aE[4], bE[4], aO[4], bO[4];        // even/odd ping-pong frag sets

#pragma unroll
    for (int f = 0; f < 4; ++f) {
        aE[f] = *(const bf16x8*)(pA[f]);
        bE[f] = *(const bf16x8*)(pB[f]);
    }

#pragma unroll
    for (int t = 0; t < NT; ++t) {
        // prefetch t+1 into the other set (compiler hoists; auto s_waitcnt)
        if (t + 1 < NT) {
            int ko = (t + 1) * BK;
            if ((t & 1) == 0) {
#pragma unroll
                for (int f = 0; f < 4; ++f) {
                    aO[f] = *(const bf16x8*)(pA[f] + ko);
                    bO[f] = *(const bf16x8*)(pB[f] + ko);
                }
            } else {
#pragma unroll
                for (int f = 0; f < 4; ++f) {
                    aE[f] = *(const bf16x8*)(pA[f] + ko);
                    bE[f] = *(const bf16x8*)(pB[f] + ko);
                }
            }
        }
        if ((t & 1) == 0) {
#pragma unroll
            for (int im = 0; im < 4; ++im)
#pragma unroll
                for (int in = 0; in < 4; ++in)
                    acc[im][in] = __builtin_amdgcn_mfma_f32_16x16x32_bf16(aE[im], bE[in], acc[im][in], 0, 0, 0);
        } else {
#pragma unroll
            for (int im = 0; im < 4; ++im)
#pragma unroll
                for (int in = 0; in < 4; ++in)
                    acc[im][in] = __builtin_amdgcn_mfma_f32_16x16x32_bf16(aO[im], bO[in], acc[im][in], 0, 0, 0);
        }
    }

    // epilogue: D = nA + nB - 2*dot -> exp -> predicate -> bucket sums
    float inv_scale = invscale_p[0];
    int ibase = i0 + wr * 64;
    int jbase = j0 + wc * 64;
    float nBv[4];
    int labBv[4], grpBv[4];
#pragma unroll
    for (int in = 0; in < 4; ++in) {
        int j = jbase + in * 16 + l15;
        nBv[in] = nB[j];
        labBv[in] = labels[j];
        grpBv[in] = groups[j];
    }
    float cs[4] = {0.0f, 0.0f, 0.0f, 0.0f};   // sym col sums (c > r)
#pragma unroll
    for (int im = 0; im < 4; ++im) {
#pragma unroll
        for (int j = 0; j < 4; ++j) {
            int row = ibase + im * 16 + l4 * 4 + j;
            float ni = nA[row];
            int li = labels[row];
            int gi = groups[row];
            float s0 = 0.0f, s1 = 0.0f;
#pragma unroll
            for (int in = 0; in < 4; ++in) {
                float d = ni + nBv[in] - 2.0f * acc[im][in][j];
                d = fmaxf(d, 1e-12f);
                float kv = __expf(-d * inv_scale);
                bool ok = (li == labBv[in]);
                if (mode == 1) ok = ok && (gi == grpBv[in]);
                if (mode == 2) {
                    s0 += (ok && grpBv[in] == 0) ? kv : 0.0f;
                    s1 += (ok && grpBv[in] == 1) ? kv : 0.0f;
                } else {
                    int c = jbase + in * 16 + l15;
                    s0     += (ok && c >= row) ? kv : 0.0f;
                    cs[in] += (ok && c >  row) ? kv : 0.0f;
                }
            }
#pragma unroll
            for (int o = 1; o < 16; o <<= 1) {
                s0 += __shfl_xor(s0, o);
                if (mode == 2) s1 += __shfl_xor(s1, o);
            }
            if (l15 == 0) {
                if (mode == 0)      atomicAdd(&lbkt[li], s0);
                else if (mode == 1) atomicAdd(&lbkt[2 * li + gi], s0);
                else {
                    atomicAdd(&lbkt[2 * li],     s0);
                    atomicAdd(&lbkt[2 * li + 1], s1);
                }
            }
        }
    }
    if (mode != 2) {
#pragma unroll
        for (int in = 0; in < 4; ++in) {
            cs[in] += __shfl_xor(cs[in], 16);
            cs[in] += __shfl_xor(cs[in], 32);
        }
        if (l4 == 0) {
#pragma unroll
            for (int in = 0; in < 4; ++in) {
                int bkt = (mode == 0) ? labBv[in] : (2 * labBv[in] + grpBv[in]);
                atomicAdd(&lbkt[bkt], cs[in]);
            }
        }
    }
    __syncthreads();
    int lim = (mode == 0) ? 10 : 20;
    if (tid < lim) {
        int off = (mode == 0) ? 0 : ((mode == 1) ? 10 : 30);
        atomicAdd(&gbkt[off + tid], lbkt[tid]);
    }
}

// ---------------------------------------------------------------------------
// Kernel 3: final combine. (unchanged from round 16)
// ---------------------------------------------------------------------------
__global__ void k_out(const int* __restrict__ labels, const int* __restrict__ groups,
                      const float* __restrict__ gbkt, float* __restrict__ out) {
    __shared__ float red[30];
    int tid = threadIdx.x;
    float cT[NC] = {}, cS[NC * NG] = {};
    for (int i = tid; i < NN; i += 256) {
        int l = labels[i], g = groups[i];
#pragma unroll
        for (int c = 0; c < NC; ++c) {
            bool m = (l == c);
            cT[c]         += m ? 1.0f : 0.0f;
            cS[2 * c]     += (m && g == 0) ? 1.0f : 0.0f;
            cS[2 * c + 1] += (m && g == 1) ? 1.0f : 0.0f;
        }
    }
#pragma unroll
    for (int o = 32; o; o >>= 1) {
#pragma unroll
        for (int c = 0; c < NC; ++c) cT[c] += __shfl_xor(cT[c], o);
#pragma unroll
        for (int p = 0; p < NC * NG; ++p) cS[p] += __shfl_xor(cS[p], o);
    }
    if (tid < 30) red[tid] = 0.0f;
    __syncthreads();
    if ((tid & 63) == 0) {
#pragma unroll
        for (int c = 0; c < NC; ++c) atomicAdd(&red[c], cT[c]);
#pragma unroll
        for (int p = 0; p < NC * NG; ++p) atomicAdd(&red[10 + p], cS[p]);
    }
    __syncthreads();
    if (tid == 0) {
        float total = 0.0f;
        for (int c = 0; c < NC; ++c) {
            float ntc = red[c];
            float sn = fmaxf(ntc, 1.0f);
            float meanTT = gbkt[c] / (sn * sn);
            for (int g = 0; g < NG; ++g) {
                float nsg = red[10 + 2 * c + g];
                float ss = fmaxf(nsg, 1.0f);
                float meanSS = gbkt[10 + 2 * c + g] / (ss * ss);
                float meanTS = gbkt[30 + 2 * c + g] / (sn * ss);
                if (ntc > 0.0f && nsg > 0.0f)
                    total += meanTT + meanSS - 2.0f * meanTS;
            }
        }
        out[0] = 0.5f * total;
    }
}

// ---------------------------------------------------------------------------
// workspace layout:
// bytes [0, 4MB)      : teacher bf16 [4096][512]
// bytes [4MB, 8MB)    : student bf16 [4096][512]
// floats from 8MB (wsf):
//   +0      nt[4096]
//   +4096   ns[4096]
//   +8192   gbkt[64]       (zeroed by prep block 0)
//   +8256   invscale[1]    (written by last heavy prep block)
//   +8257   cnt (uint)     (zeroed by hipMemsetAsync)
//   +8260   ssq[64]
//   +8324   psum[64*512]   (fully overwritten each call)
// ---------------------------------------------------------------------------
extern "C" void kernel_launch(void* const* d_in, const int* in_sizes, int n_in,
                              void* d_out, int out_size, void* d_ws, size_t ws_size,
                              hipStream_t stream) {
    const float* fs     = (const float*)d_in[0];
    const float* ft     = (const float*)d_in[1];
    const int*   groups = (const int*)d_in[2];
    const int*   labels = (const int*)d_in[3];

    __bf16* Abf = (__bf16*)d_ws;                       // teacher
    __bf16* Bbf = (__bf16*)d_ws + (size_t)NN * DD;     // student
    float* wsf  = (float*)((char*)d_ws + (size_t)2 * NN * DD * sizeof(__bf16));
    float* nt   = wsf;
    float* ns   = wsf + 4096;
    float* gbkt = wsf + 8192;
    float* invs = wsf + 8256;
    unsigned int* cnt = (unsigned int*)(wsf + 8257);
    float* ssq  = wsf + 8260;
    float* psum = wsf + 8324;

    hipMemsetAsync(cnt, 0, sizeof(unsigned int), stream);
    k_prep<<<1024, 256, 0, stream>>>(ft, fs, Abf, Bbf, nt, ns, psum, ssq,
                                     gbkt, invs, cnt);
    k_gram_all<<<NTILES, 256, 0, stream>>>(Abf, Bbf, nt, ns, labels, groups,
                                           invs, gbkt);
    k_out<<<1, 256, 0, stream>>>(labels, groups, gbkt, (float*)d_out);
}

// Round 19
// 134.119 us; speedup vs baseline: 1.5845x; 1.5845x over previous
//
#include <hip/hip_runtime.h>
#include <math.h>

#define NN 4096
#define DD 512
#define NC 10
#define NG 2

#define BM 128
#define BN 128
#define BK 32
#define NT (DD / BK)     // 16 K-steps
#define NTILES 2080      // 528 TT + 528 SS + 1024 TS (= 8 * 260)

typedef __bf16 bf16x8 __attribute__((ext_vector_type(8)));
typedef __bf16 bf16x4 __attribute__((ext_vector_type(4)));
typedef float f32x4 __attribute__((ext_vector_type(4)));

__device__ __forceinline__ void load_lds16(const __bf16* g, __bf16* l) {
    __builtin_amdgcn_global_load_lds((const __attribute__((address_space(1))) void*)g,
                                     (__attribute__((address_space(3))) void*)l, 16, 0, 0);
}

__device__ __forceinline__ float agent_ld(const float* p) {
    return __hip_atomic_load(p, __ATOMIC_RELAXED, __HIP_MEMORY_SCOPE_AGENT);
}

// ---------------------------------------------------------------------------
// Kernel 1 (fused): fp32->bf16 convert + per-row norms (all 1024 blocks)
// + column sums / sumsq partials (blocks 0..63) + last-heavy-block invscale
// + label/group bucket counts (light block 512 -> cnts[30], moved from k_out).
// ---------------------------------------------------------------------------
__global__ void k_prep(const float* __restrict__ ft, const float* __restrict__ fs,
                       const int* __restrict__ labels, const int* __restrict__ groups,
                       __bf16* __restrict__ at, __bf16* __restrict__ as_,
                       float* __restrict__ nt, float* __restrict__ ns,
                       float* __restrict__ psum, float* __restrict__ ssq,
                       float* __restrict__ gbkt, float* __restrict__ cnts,
                       float* __restrict__ invscale, unsigned int* __restrict__ cnt) {
    int tid = threadIdx.x;
    if (blockIdx.x == 0 && tid < 64) gbkt[tid] = 0.0f;

    int wid  = tid >> 6;
    int lane = tid & 63;
    int r = blockIdx.x * 4 + wid;             // 0..4095
    const float4* pt = (const float4*)(ft + (size_t)r * DD);
    const float4* ps = (const float4*)(fs + (size_t)r * DD);
    float st = 0.0f, ss = 0.0f;
#pragma unroll
    for (int c = 0; c < 2; ++c) {
        float4 vt = pt[lane + 64 * c];
        float4 vs = ps[lane + 64 * c];
        st += vt.x * vt.x + vt.y * vt.y + vt.z * vt.z + vt.w * vt.w;
        ss += vs.x * vs.x + vs.y * vs.y + vs.z * vs.z + vs.w * vs.w;
        bf16x4 bt, bs;
        bt[0] = (__bf16)vt.x; bt[1] = (__bf16)vt.y; bt[2] = (__bf16)vt.z; bt[3] = (__bf16)vt.w;
        bs[0] = (__bf16)vs.x; bs[1] = (__bf16)vs.y; bs[2] = (__bf16)vs.z; bs[3] = (__bf16)vs.w;
        *(bf16x4*)(at  + (size_t)r * DD + (lane + 64 * c) * 4) = bt;
        *(bf16x4*)(as_ + (size_t)r * DD + (lane + 64 * c) * 4) = bs;
    }
#pragma unroll
    for (int o = 32; o; o >>= 1) { st += __shfl_xor(st, o); ss += __shfl_xor(ss, o); }
    if (lane == 0) { nt[r] = st; ns[r] = ss; }

    // ---- block 512 (light): label/group counts via register buckets ----
    if (blockIdx.x == 512) {
        float cT[NC] = {}, cS[NC * NG] = {};
        for (int i = tid; i < NN; i += 256) {
            int l = labels[i], g = groups[i];
#pragma unroll
            for (int c = 0; c < NC; ++c) {
                bool m = (l == c);
                cT[c]         += m ? 1.0f : 0.0f;
                cS[2 * c]     += (m && g == 0) ? 1.0f : 0.0f;
                cS[2 * c + 1] += (m && g == 1) ? 1.0f : 0.0f;
            }
        }
#pragma unroll
        for (int o = 32; o; o >>= 1) {
#pragma unroll
            for (int c = 0; c < NC; ++c) cT[c] += __shfl_xor(cT[c], o);
#pragma unroll
            for (int p = 0; p < NC * NG; ++p) cS[p] += __shfl_xor(cS[p], o);
        }
        __shared__ float redc[30];
        if (tid < 30) redc[tid] = 0.0f;
        __syncthreads();
        if ((tid & 63) == 0) {
#pragma unroll
            for (int c = 0; c < NC; ++c) atomicAdd(&redc[c], cT[c]);
#pragma unroll
            for (int p = 0; p < NC * NG; ++p) atomicAdd(&redc[10 + p], cS[p]);
        }
        __syncthreads();
        if (tid < 30) cnts[tid] = redc[tid];
        return;
    }

    if (blockIdx.x >= 64) return;
    int b = blockIdx.x;
    const float* src = (b < 32) ? ft : fs;
    int r0 = (b & 31) * 128;
    int c0 = tid, c1 = tid + 256;
    float a0 = 0.0f, a1 = 0.0f, sq = 0.0f;
    for (int rr = r0; rr < r0 + 128; ++rr) {
        float v0 = src[(size_t)rr * DD + c0];
        float v1 = src[(size_t)rr * DD + c1];
        a0 += v0; a1 += v1;
        sq += v0 * v0 + v1 * v1;
    }
    psum[(size_t)b * 512 + c0] = a0;
    psum[(size_t)b * 512 + c1] = a1;
#pragma unroll
    for (int o = 32; o; o >>= 1) sq += __shfl_xor(sq, o);
    __shared__ float redsq[4];
    if (lane == 0) redsq[wid] = sq;
    __syncthreads();
    if (tid == 0) ssq[b] = redsq[0] + redsq[1] + redsq[2] + redsq[3];

    __shared__ int amLast;
    __threadfence();
    __syncthreads();
    if (tid == 0) amLast = (atomicAdd(cnt, 1u) == 63u) ? 1 : 0;
    __syncthreads();
    if (!amLast) return;
    __threadfence();

    __shared__ float red[8];
    float s = (tid < 64) ? agent_ld(&ssq[tid]) : 0.0f;
    float d = 0.0f;
    for (int col = tid; col < DD; col += 256) {
        float su = 0.0f, sv = 0.0f;
#pragma unroll
        for (int p = 0; p < 32; ++p) {
            su += agent_ld(&psum[(size_t)p * 512 + col]);
            sv += agent_ld(&psum[(size_t)(p + 32) * 512 + col]);
        }
        d += su * sv;
    }
#pragma unroll
    for (int o = 32; o; o >>= 1) { s += __shfl_xor(s, o); d += __shfl_xor(d, o); }
    if (lane == 0) { red[wid] = s; red[wid + 4] = d; }
    __syncthreads();
    if (tid == 0) {
        float S  = red[0] + red[1] + red[2] + red[3];
        float Dt = red[4] + red[5] + red[6] + red[7];
        float sigma = S / (float)NN - 2.0f * Dt / ((float)NN * (float)NN);
        invscale[0] = 1.0f / (2.0f * sigma);
    }
}

// ---------------------------------------------------------------------------
// Kernel 2: all three Grams. BYTE-IDENTICAL to round 16 (best measured):
// 128x128, 4 waves (2x2), wave tile 64x64, BK=32, 3-buffer depth-2
// counted-vmcnt pipeline (steady vmcnt(4)), conflict-free [kq][row][8] LDS,
// swz=(bid&7)*260+bid>>3; LDS bucket epilogue -> <=20 atomics into gbkt[50].
// ---------------------------------------------------------------------------
__global__ __launch_bounds__(256, 3) void k_gram_all(
    const __bf16* __restrict__ T, const __bf16* __restrict__ S,
    const float* __restrict__ nt, const float* __restrict__ ns,
    const int* __restrict__ labels, const int* __restrict__ groups,
    const float* __restrict__ invscale_p, float* __restrict__ gbkt) {

    __shared__ __bf16 As[3][4 * 128 * 8];   // 8 KB per buffer
    __shared__ __bf16 Bs[3][4 * 128 * 8];   // 8 KB per buffer
    __shared__ float lbkt[20];

    int swz = ((int)blockIdx.x & 7) * 260 + ((int)blockIdx.x >> 3);
    int mode, bi, bj;
    if (swz < 1056) {
        mode = (swz < 528) ? 0 : 1;
        int k = (swz < 528) ? swz : swz - 528;
        int t = 0;
        while (k >= 32 - t) { k -= 32 - t; ++t; }   // uniform, <=32 iters
        bi = t; bj = t + k;
    } else {
        mode = 2;
        int k = swz - 1056;
        bi = k >> 5; bj = k & 31;
    }

    const __bf16* A = (mode == 1) ? S : T;
    const __bf16* B = (mode == 0) ? T : S;
    const float* nA = (mode == 1) ? ns : nt;
    const float* nB = (mode == 0) ? nt : ns;

    int tid = threadIdx.x;
    if (tid < 20) lbkt[tid] = 0.0f;          // covered by prologue barrier
    int i0 = bi * BM;
    int j0 = bj * BN;

    int lane = tid & 63, wid = tid >> 6;
    int wr = wid >> 1, wc = wid & 1;          // 2 x 2 wave grid
    int l15 = lane & 15, l4 = lane >> 4;

    int ra = tid & 127;
    int qa = tid >> 7;                        // 0..1
    const __bf16* gA = A + (size_t)(i0 + ra) * DD + qa * 8;   // +16 = chunk qa+2
    const __bf16* gB = B + (size_t)(j0 + ra) * DD + qa * 8;

    f32x4 acc[4][4] = {};

#define STAGE(bb, tt)                                                          \
    do {                                                                       \
        int _k0 = (tt) * BK;                                                   \
        load_lds16(gA + _k0,      &As[(bb)][(size_t)tid * 8]);                 \
        load_lds16(gA + _k0 + 16, &As[(bb)][(size_t)(tid + 256) * 8]);         \
        load_lds16(gB + _k0,      &Bs[(bb)][(size_t)tid * 8]);                 \
        load_lds16(gB + _k0 + 16, &Bs[(bb)][(size_t)(tid + 256) * 8]);         \
    } while (0)

    STAGE(0, 0);
    STAGE(1, 1);
    asm volatile("s_waitcnt vmcnt(4)" ::: "memory");
    __builtin_amdgcn_s_barrier();
    __builtin_amdgcn_sched_barrier(0);

#pragma unroll
    for (int t = 0; t < NT; ++t) {
        int b = t % 3;
        bf16x8 af[4], bfr[4];
#pragma unroll
        for (int im = 0; im < 4; ++im)
            af[im] = *(const bf16x8*)&As[b][((size_t)l4 * 128 + wr * 64 + im * 16 + l15) * 8];
#pragma unroll
        for (int in = 0; in < 4; ++in)
            bfr[in] = *(const bf16x8*)&Bs[b][((size_t)l4 * 128 + wc * 64 + in * 16 + l15) * 8];
        if (t + 2 < NT) STAGE((t + 2) % 3, t + 2);
#pragma unroll
        for (int im = 0; im < 4; ++im)
#pragma unroll
            for (int in = 0; in < 4; ++in)
                acc[im][in] = __builtin_amdgcn_mfma_f32_16x16x32_bf16(af[im], bfr[in], acc[im][in], 0, 0, 0);
        if (t + 1 < NT) {
            if (t + 2 < NT) asm volatile("s_waitcnt vmcnt(4)" ::: "memory");
            else            asm volatile("s_waitcnt vmcnt(0)" ::: "memory");
            __builtin_amdgcn_s_barrier();
            __builtin_amdgcn_sched_barrier(0);
        }
    }
#undef STAGE

    // epilogue: D = nA + nB - 2*dot -> exp -> predicate -> bucket sums
    float inv_scale = invscale_p[0];
    int ibase = i0 + wr * 64;
    int jbase = j0 + wc * 64;
    float nBv[4];
    int labBv[4], grpBv[4];
#pragma unroll
    for (int in = 0; in < 4; ++in) {
        int j = jbase + in * 16 + l15;
        nBv[in] = nB[j];
        labBv[in] = labels[j];
        grpBv[in] = groups[j];
    }
    float cs[4] = {0.0f, 0.0f, 0.0f, 0.0f};   // sym col sums (c > r)
#pragma unroll
    for (int im = 0; im < 4; ++im) {
#pragma unroll
        for (int j = 0; j < 4; ++j) {
            int row = ibase + im * 16 + l4 * 4 + j;
            float ni = nA[row];
            int li = labels[row];
            int gi = groups[row];
            float s0 = 0.0f, s1 = 0.0f;
#pragma unroll
            for (int in = 0; in < 4; ++in) {
                float d = ni + nBv[in] - 2.0f * acc[im][in][j];
                d = fmaxf(d, 1e-12f);
                float kv = __expf(-d * inv_scale);
                bool ok = (li == labBv[in]);
                if (mode == 1) ok = ok && (gi == grpBv[in]);
                if (mode == 2) {
                    s0 += (ok && grpBv[in] == 0) ? kv : 0.0f;
                    s1 += (ok && grpBv[in] == 1) ? kv : 0.0f;
                } else {
                    int c = jbase + in * 16 + l15;
                    s0     += (ok && c >= row) ? kv : 0.0f;
                    cs[in] += (ok && c >  row) ? kv : 0.0f;
                }
            }
#pragma unroll
            for (int o = 1; o < 16; o <<= 1) {
                s0 += __shfl_xor(s0, o);
                if (mode == 2) s1 += __shfl_xor(s1, o);
            }
            if (l15 == 0) {
                if (mode == 0)      atomicAdd(&lbkt[li], s0);
                else if (mode == 1) atomicAdd(&lbkt[2 * li + gi], s0);
                else {
                    atomicAdd(&lbkt[2 * li],     s0);
                    atomicAdd(&lbkt[2 * li + 1], s1);
                }
            }
        }
    }
    if (mode != 2) {
#pragma unroll
        for (int in = 0; in < 4; ++in) {
            cs[in] += __shfl_xor(cs[in], 16);
            cs[in] += __shfl_xor(cs[in], 32);
        }
        if (l4 == 0) {
#pragma unroll
            for (int in = 0; in < 4; ++in) {
                int bkt = (mode == 0) ? labBv[in] : (2 * labBv[in] + grpBv[in]);
                atomicAdd(&lbkt[bkt], cs[in]);
            }
        }
    }
    __syncthreads();
    int lim = (mode == 0) ? 10 : 20;
    if (tid < lim) {
        int off = (mode == 0) ? 0 : ((mode == 1) ? 10 : 30);
        atomicAdd(&gbkt[off + tid], lbkt[tid]);
    }
}

// ---------------------------------------------------------------------------
// Kernel 3: slim final combine. Parallel-load cnts[30] + gbkt[50] into LDS
// (one memory latency), thread 0 combines 80 floats -> scalar.
// ---------------------------------------------------------------------------
__global__ void k_out(const float* __restrict__ cnts, const float* __restrict__ gbkt,
                      float* __restrict__ out) {
    __shared__ float sh[80];
    int tid = threadIdx.x;
    if (tid < 30) sh[tid] = cnts[tid];
    else if (tid < 80) sh[tid] = gbkt[tid - 30];
    __syncthreads();
    if (tid == 0) {
        float total = 0.0f;
        for (int c = 0; c < NC; ++c) {
            float ntc = sh[c];
            float sn = fmaxf(ntc, 1.0f);
            float meanTT = sh[30 + c] / (sn * sn);
            for (int g = 0; g < NG; ++g) {
                float nsg = sh[10 + 2 * c + g];
                float ss = fmaxf(nsg, 1.0f);
                float meanSS = sh[40 + 2 * c + g] / (ss * ss);
                float meanTS = sh[60 + 2 * c + g] / (sn * ss);
                if (ntc > 0.0f && nsg > 0.0f)
                    total += meanTT + meanSS - 2.0f * meanTS;
            }
        }
        out[0] = 0.5f * total;
    }
}

// ---------------------------------------------------------------------------
// workspace layout:
// bytes [0, 4MB)      : teacher bf16 [4096][512]
// bytes [4MB, 8MB)    : student bf16 [4096][512]
// floats from 8MB (wsf):
//   +0      nt[4096]
//   +4096   ns[4096]
//   +8192   gbkt[64]       (zeroed by prep block 0)
//   +8256   invscale[1]    (written by last heavy prep block)
//   +8257   cnt (uint)     (zeroed by hipMemsetAsync)
//   +8260   ssq[64]
//   +8324   cnts[30]       (written by prep block 512)
//   +8356   psum[64*512]   (fully overwritten each call)
// ---------------------------------------------------------------------------
extern "C" void kernel_launch(void* const* d_in, const int* in_sizes, int n_in,
                              void* d_out, int out_size, void* d_ws, size_t ws_size,
                              hipStream_t stream) {
    const float* fs     = (const float*)d_in[0];
    const float* ft     = (const float*)d_in[1];
    const int*   groups = (const int*)d_in[2];
    const int*   labels = (const int*)d_in[3];

    __bf16* Abf = (__bf16*)d_ws;                       // teacher
    __bf16* Bbf = (__bf16*)d_ws + (size_t)NN * DD;     // student
    float* wsf  = (float*)((char*)d_ws + (size_t)2 * NN * DD * sizeof(__bf16));
    float* nt   = wsf;
    float* ns   = wsf + 4096;
    float* gbkt = wsf + 8192;
    float* invs = wsf + 8256;
    unsigned int* cnt = (unsigned int*)(wsf + 8257);
    float* ssq  = wsf + 8260;
    float* cnts = wsf + 8324;
    float* psum = wsf + 8356;

    hipMemsetAsync(cnt, 0, sizeof(unsigned int), stream);
    k_prep<<<1024, 256, 0, stream>>>(ft, fs, labels, groups, Abf, Bbf, nt, ns,
                                     psum, ssq, gbkt, cnts, invs, cnt);
    k_gram_all<<<NTILES, 256, 0, stream>>>(Abf, Bbf, nt, ns, labels, groups,
                                           invs, gbkt);
    k_out<<<128, 128, 0, stream>>>(cnts, gbkt, (float*)d_out);
}